// Round 6
// baseline (264.721 us; speedup 1.0000x reference)
//
#include <hip/hip_runtime.h>

// Segment-sum over sorted ray indices + gather-back, no atomics.
//   d_in[0]: sample_values f32 [n_samples * D]
//   d_in[1]: ray_indices  i32 [n_samples] (sorted, non-decreasing)
//   d_in[2]: n_rays (device scalar, unused -- derived from sizes)
//   d_out  : [n_rays*D] per-ray sums, then [n_samples*D] per-sample gathered sums
//
// Kernel A: per-sample boundary scatter -> seg_start[r], seg_end[r] (d_ws,
//           memset 0xFF so empty rays read -1).
// Kernel B: one wave per ray. Lane l = (slot l>>2 in [0,16)) x (channel-pair
//           l&3). Loads float2 -> wave reads 512 B contiguous per iteration
//           (16 samples). One 4-step shfl_xor reduce per RAY (vs per-window
//           scans before). Plain stores for per-ray output (each ray owned by
//           exactly one wave -> zero atomics, no output memset), then the same
//           wave broadcasts its sum over its samples with contiguous 512 B
//           stores -> the separate gather pass is eliminated entirely.

#define DCH 8

__global__ void __launch_bounds__(256) bounds_kernel(
    const int* __restrict__ rays,
    int* __restrict__ seg_start,
    int* __restrict__ seg_end,
    int n_samples) {
  long i = (long)blockIdx.x * blockDim.x + threadIdx.x;
  if (i >= n_samples) return;
  int r = rays[i];
  if (i == 0 || rays[i - 1] != r) seg_start[r] = (int)i;
  if (i == n_samples - 1 || rays[i + 1] != r) seg_end[r] = (int)(i + 1);
}

__global__ void __launch_bounds__(256) raysum_kernel(
    const float2* __restrict__ vals2,
    const int* __restrict__ seg_start,
    const int* __restrict__ seg_end,
    float* __restrict__ out_ray,
    float2* __restrict__ out_sample2,
    int n_rays) {
  int wave = blockIdx.x * (blockDim.x >> 6) + (threadIdx.x >> 6);
  if (wave >= n_rays) return;
  const int lane = threadIdx.x & 63;
  const int sl = lane >> 2;   // sample slot within window [0,16)
  const int ch2 = lane & 3;   // channel pair: floats 2*ch2, 2*ch2+1

  const int s0 = seg_start[wave];
  const int s1 = (s0 >= 0) ? seg_end[wave] : 0;

  float2 acc = {0.f, 0.f};
  if (s0 >= 0) {
    for (int j = s0 + sl; j < s1; j += 16) {
      float2 v = vals2[(long)j * 4 + ch2];
      acc.x += v.x;
      acc.y += v.y;
    }
  }

  // Reduce across the 16 sample slots (lane bits 2..5); every lane ends with
  // the full sum for its channel pair.
#pragma unroll
  for (int off = 4; off <= 32; off <<= 1) {
    acc.x += __shfl_xor(acc.x, off, 64);
    acc.y += __shfl_xor(acc.y, off, 64);
  }

  // Per-ray output: lanes 0..3 cover the 8 channels. Written for EVERY ray
  // (zeros for empty rays) -> no output memset needed.
  if (lane < 4) {
    *reinterpret_cast<float2*>(out_ray + (long)wave * DCH + 2 * lane) = acc;
  }

  // Broadcast the ray sum back over this ray's samples (contiguous 512 B
  // stores per iteration).
  if (s0 >= 0) {
    for (int j = s0 + sl; j < s1; j += 16) {
      out_sample2[(long)j * 4 + ch2] = acc;
    }
  }
}

extern "C" void kernel_launch(void* const* d_in, const int* in_sizes, int n_in,
                              void* d_out, int out_size, void* d_ws, size_t ws_size,
                              hipStream_t stream) {
  const float* vals = (const float*)d_in[0];
  const int* rays   = (const int*)d_in[1];

  const int n_samples = in_sizes[1];
  const int d         = in_sizes[0] / n_samples;   // = 8
  const int n_rays    = out_size / d - n_samples;  // = 65536

  float* out_ray    = (float*)d_out;
  float* out_sample = out_ray + (size_t)n_rays * d;

  int* seg_start = (int*)d_ws;
  int* seg_end   = seg_start + n_rays;

  // -1 init so empty rays are detected (harness poisons d_ws each launch).
  (void)hipMemsetAsync(seg_start, 0xFF, (size_t)2 * n_rays * sizeof(int), stream);

  bounds_kernel<<<(int)(((long)n_samples + 255) / 256), 256, 0, stream>>>(
      rays, seg_start, seg_end, n_samples);

  // One wave per ray: 4 waves per 256-thread block.
  const int nblocks = (n_rays + 3) / 4;
  raysum_kernel<<<nblocks, 256, 0, stream>>>(
      reinterpret_cast<const float2*>(vals), seg_start, seg_end,
      out_ray, reinterpret_cast<float2*>(out_sample), n_rays);
}